// Round 1
// baseline (481.022 us; speedup 1.0000x reference)
//
#include <hip/hip_runtime.h>
#include <hip/hip_bf16.h>

#define D 128
#define SLOPE 0.2f

// ---------- counting sort of edges by dst ----------

__global__ void hist_kernel(const int* __restrict__ dst, int* __restrict__ counts, int E) {
  int i = blockIdx.x * blockDim.x + threadIdx.x;
  if (i < E) atomicAdd(&counts[dst[i]], 1);
}

__global__ __launch_bounds__(1024) void scan_kernel(const int* __restrict__ counts,
                                                    int* __restrict__ offsets,
                                                    int* __restrict__ cursor, int n) {
  __shared__ int sums[1024];
  int t = threadIdx.x;
  int per = (n + 1023) >> 10;
  int lo = t * per;
  int hi = lo + per;
  if (lo > n) lo = n;
  if (hi > n) hi = n;
  int s = 0;
  for (int i = lo; i < hi; ++i) s += counts[i];
  sums[t] = s;
  __syncthreads();
  for (int d = 1; d < 1024; d <<= 1) {
    int v = (t >= d) ? sums[t - d] : 0;
    __syncthreads();
    sums[t] += v;
    __syncthreads();
  }
  int excl = (t == 0) ? 0 : sums[t - 1];
  for (int i = lo; i < hi; ++i) {
    offsets[i] = excl;
    cursor[i] = excl;
    excl += counts[i];
  }
  if (t == 1023) offsets[n] = sums[1023];
}

__global__ void scatter_kernel(const int* __restrict__ dst, int* __restrict__ cursor,
                               int* __restrict__ perm, int E) {
  int i = blockIdx.x * blockDim.x + threadIdx.x;
  if (i < E) {
    int p = atomicAdd(&cursor[dst[i]], 1);
    perm[p] = i;
  }
}

// ---------- W transpose: wcatT[k][c] = (c<128 ? Wl[c][k] : Wr[c-128][k]) ----------

__global__ void transpose_w(const float* __restrict__ Wl, const float* __restrict__ Wr,
                            float* __restrict__ wcatT) {
  int i = blockIdx.x * blockDim.x + threadIdx.x;  // 0..32767
  int k = i >> 8, c = i & 255;
  float v = (c < D) ? Wl[c * D + k] : Wr[(c - D) * D + k];
  wcatT[k * 256 + c] = v;
}

// ---------- f32 GEMM: hl = x@Wl^T + bl, hr = x@Wr^T + br ----------
// 64 rows x 256 cols (hl||hr) per block, 8x8 per thread.

__global__ __launch_bounds__(256) void gemm_hlr(const float* __restrict__ x,
    const float* __restrict__ wcatT, const float* __restrict__ bl,
    const float* __restrict__ br, float* __restrict__ hl, float* __restrict__ hr,
    int nrows) {
  __shared__ float xs[64 * 128];
  int t = threadIdx.x;
  int row0 = blockIdx.x << 6;
#pragma unroll
  for (int i = 0; i < 8; ++i) {
    int g = t + (i << 8);
    int r = g >> 5, c4 = (g & 31) << 2;
    int gr = row0 + r;
    float4 v = make_float4(0.f, 0.f, 0.f, 0.f);
    if (gr < nrows) v = *(const float4*)(x + (size_t)gr * D + c4);
    *(float4*)(xs + r * 128 + c4) = v;
  }
  __syncthreads();
  int rg = t >> 5, cg = t & 31;
  int r0 = rg << 3, c0 = cg << 3;
  float acc[8][8];
#pragma unroll
  for (int i = 0; i < 8; ++i)
#pragma unroll
    for (int j = 0; j < 8; ++j) acc[i][j] = 0.f;

  for (int kk = 0; kk < 128; kk += 4) {
    float4 xv[8];
#pragma unroll
    for (int i = 0; i < 8; ++i) xv[i] = *(const float4*)(xs + (r0 + i) * 128 + kk);
#pragma unroll
    for (int dk = 0; dk < 4; ++dk) {
      float4 wa = *(const float4*)(wcatT + (kk + dk) * 256 + c0);
      float4 wb = *(const float4*)(wcatT + (kk + dk) * 256 + c0 + 4);
      float wv0 = wa.x, wv1 = wa.y, wv2 = wa.z, wv3 = wa.w;
      float wv4 = wb.x, wv5 = wb.y, wv6 = wb.z, wv7 = wb.w;
#pragma unroll
      for (int i = 0; i < 8; ++i) {
        float xk = (dk == 0) ? xv[i].x : (dk == 1) ? xv[i].y : (dk == 2) ? xv[i].z : xv[i].w;
        acc[i][0] = fmaf(xk, wv0, acc[i][0]);
        acc[i][1] = fmaf(xk, wv1, acc[i][1]);
        acc[i][2] = fmaf(xk, wv2, acc[i][2]);
        acc[i][3] = fmaf(xk, wv3, acc[i][3]);
        acc[i][4] = fmaf(xk, wv4, acc[i][4]);
        acc[i][5] = fmaf(xk, wv5, acc[i][5]);
        acc[i][6] = fmaf(xk, wv6, acc[i][6]);
        acc[i][7] = fmaf(xk, wv7, acc[i][7]);
      }
    }
  }
  float bias[8];
#pragma unroll
  for (int j = 0; j < 8; ++j) bias[j] = (c0 < D) ? bl[c0 + j] : br[c0 - D + j];
#pragma unroll
  for (int i = 0; i < 8; ++i) {
    int gr = row0 + r0 + i;
    if (gr >= nrows) continue;
    float* base = (c0 < D) ? (hl + (size_t)gr * D + c0) : (hr + (size_t)gr * D + (c0 - D));
    float4 o0 = make_float4(acc[i][0] + bias[0], acc[i][1] + bias[1],
                            acc[i][2] + bias[2], acc[i][3] + bias[3]);
    float4 o1 = make_float4(acc[i][4] + bias[4], acc[i][5] + bias[5],
                            acc[i][6] + bias[6], acc[i][7] + bias[7]);
    *(float4*)(base) = o0;
    *(float4*)(base + 4) = o1;
  }
}

// ---------- per-node fused softmax + aggregation (1 wave per node) ----------

__global__ __launch_bounds__(256) void node_attn(const float* __restrict__ x,
    const float* __restrict__ alpha, const float* __restrict__ hl,
    const float* __restrict__ hr, const int* __restrict__ src,
    const int* __restrict__ perm, const int* __restrict__ offsets,
    float* __restrict__ out, int n) {
  int wid = threadIdx.x >> 6, lane = threadIdx.x & 63;
  int v = (blockIdx.x << 2) + wid;
  if (v >= n) return;
  int b = offsets[v], e = offsets[v + 1];
  int ch = lane << 1;
  float2 hrv = *(const float2*)(hr + (size_t)v * D + ch);
  float dx = 0.f, dy = 0.f, ox = 0.f, oy = 0.f;
  for (int i = b; i < e; ++i) {
    int ed = perm[i];
    int s = src[ed];
    float2 a = *(const float2*)(alpha + (size_t)ed * D + ch);
    float2 h = *(const float2*)(hl + (size_t)s * D + ch);
    float2 xv = *(const float2*)(x + (size_t)s * D + ch);
    float t0 = (h.x + hrv.x) * a.x;
    float t1 = (h.y + hrv.y) * a.y;
    t0 = (t0 >= 0.f) ? t0 : SLOPE * t0;
    t1 = (t1 >= 0.f) ? t1 : SLOPE * t1;
    float e0 = __expf(t0);
    float e1 = __expf(t1);
    dx += e0;
    dy += e1;
    ox = fmaf(xv.x, e0, ox);
    oy = fmaf(xv.y, e1, oy);
  }
  float2 r;
  r.x = (e > b) ? ox / dx : 0.f;
  r.y = (e > b) ? oy / dy : 0.f;
  *(float2*)(out + (size_t)v * D + ch) = r;
}

extern "C" void kernel_launch(void* const* d_in, const int* in_sizes, int n_in,
                              void* d_out, int out_size, void* d_ws, size_t ws_size,
                              hipStream_t stream) {
  const float* x = (const float*)d_in[0];
  const float* alpha = (const float*)d_in[1];
  const float* Wl = (const float*)d_in[2];
  const float* bl = (const float*)d_in[3];
  const float* Wr = (const float*)d_in[4];
  const float* br = (const float*)d_in[5];
  const int* src = (const int*)d_in[6];
  const int* dst = (const int*)d_in[7];
  int N = in_sizes[0] / D;
  int E = in_sizes[6];
  float* out = (float*)d_out;

  char* ws = (char*)d_ws;
  auto al = [](size_t v) { return (v + 255) & ~(size_t)255; };
  size_t off = 0;
  float* hl = (float*)(ws + off); off += al((size_t)N * D * 4);
  float* hr = (float*)(ws + off); off += al((size_t)N * D * 4);
  float* wcatT = (float*)(ws + off); off += al(128 * 256 * 4);
  int* counts = (int*)(ws + off); off += al((size_t)N * 4);
  int* offsets = (int*)(ws + off); off += al((size_t)(N + 1) * 4);
  int* cursor = (int*)(ws + off); off += al((size_t)N * 4);
  int* perm = (int*)(ws + off); off += al((size_t)E * 4);
  (void)off; (void)ws_size; (void)n_in; (void)out_size;

  const int tb = 256;
  hipMemsetAsync(counts, 0, (size_t)N * 4, stream);
  hist_kernel<<<(E + tb - 1) / tb, tb, 0, stream>>>(dst, counts, E);
  scan_kernel<<<1, 1024, 0, stream>>>(counts, offsets, cursor, N);
  scatter_kernel<<<(E + tb - 1) / tb, tb, 0, stream>>>(dst, cursor, perm, E);
  transpose_w<<<(128 * 256) / tb, tb, 0, stream>>>(Wl, Wr, wcatT);
  gemm_hlr<<<(N + 63) / 64, 256, 0, stream>>>(x, wcatT, bl, br, hl, hr, N);
  node_attn<<<(N + 3) / 4, 256, 0, stream>>>(x, alpha, hl, hr, src, perm, offsets, out, N);
}

// Round 2
// 427.827 us; speedup vs baseline: 1.1243x; 1.1243x over previous
//
#include <hip/hip_runtime.h>
#include <hip/hip_bf16.h>

#define D 128
#define SLOPE 0.2f

// ---------- counting sort of edges by dst ----------

__global__ void hist_kernel(const int* __restrict__ dst, int* __restrict__ counts, int E) {
  int i = blockIdx.x * blockDim.x + threadIdx.x;
  if (i < E) atomicAdd(&counts[dst[i]], 1);
}

__global__ __launch_bounds__(1024) void scan_kernel(const int* __restrict__ counts,
                                                    int* __restrict__ offsets,
                                                    int* __restrict__ cursor, int n) {
  __shared__ int sums[1024];
  int t = threadIdx.x;
  int per = (n + 1023) >> 10;
  int lo = t * per;
  int hi = lo + per;
  if (lo > n) lo = n;
  if (hi > n) hi = n;
  int s = 0;
  for (int i = lo; i < hi; ++i) s += counts[i];
  sums[t] = s;
  __syncthreads();
  for (int d = 1; d < 1024; d <<= 1) {
    int v = (t >= d) ? sums[t - d] : 0;
    __syncthreads();
    sums[t] += v;
    __syncthreads();
  }
  int excl = (t == 0) ? 0 : sums[t - 1];
  for (int i = lo; i < hi; ++i) {
    offsets[i] = excl;
    cursor[i] = excl;
    excl += counts[i];
  }
  if (t == 1023) offsets[n] = sums[1023];
}

__global__ void scatter_kernel(const int* __restrict__ dst, const int* __restrict__ src,
                               int* __restrict__ cursor, int* __restrict__ perm,
                               int* __restrict__ sperm, int E) {
  int i = blockIdx.x * blockDim.x + threadIdx.x;
  if (i < E) {
    int p = atomicAdd(&cursor[dst[i]], 1);
    perm[p] = i;
    sperm[p] = src[i];
  }
}

// ---------- W transpose: wcatT[k][c] = (c<128 ? Wl[c][k] : Wr[c-128][k]) ----------

__global__ void transpose_w(const float* __restrict__ Wl, const float* __restrict__ Wr,
                            float* __restrict__ wcatT) {
  int i = blockIdx.x * blockDim.x + threadIdx.x;  // 0..32767
  int k = i >> 8, c = i & 255;
  float v = (c < D) ? Wl[c * D + k] : Wr[(c - D) * D + k];
  wcatT[k * 256 + c] = v;
}

// ---------- f32 GEMM: hl = x@Wl^T + bl, hr = x@Wr^T + br ----------

__global__ __launch_bounds__(256) void gemm_hlr(const float* __restrict__ x,
    const float* __restrict__ wcatT, const float* __restrict__ bl,
    const float* __restrict__ br, float* __restrict__ hl, float* __restrict__ hr,
    int nrows) {
  __shared__ float xs[64 * 128];
  int t = threadIdx.x;
  int row0 = blockIdx.x << 6;
#pragma unroll
  for (int i = 0; i < 8; ++i) {
    int g = t + (i << 8);
    int r = g >> 5, c4 = (g & 31) << 2;
    int gr = row0 + r;
    float4 v = make_float4(0.f, 0.f, 0.f, 0.f);
    if (gr < nrows) v = *(const float4*)(x + (size_t)gr * D + c4);
    *(float4*)(xs + r * 128 + c4) = v;
  }
  __syncthreads();
  int rg = t >> 5, cg = t & 31;
  int r0 = rg << 3, c0 = cg << 3;
  float acc[8][8];
#pragma unroll
  for (int i = 0; i < 8; ++i)
#pragma unroll
    for (int j = 0; j < 8; ++j) acc[i][j] = 0.f;

  for (int kk = 0; kk < 128; kk += 4) {
    float4 xv[8];
#pragma unroll
    for (int i = 0; i < 8; ++i) xv[i] = *(const float4*)(xs + (r0 + i) * 128 + kk);
#pragma unroll
    for (int dk = 0; dk < 4; ++dk) {
      float4 wa = *(const float4*)(wcatT + (kk + dk) * 256 + c0);
      float4 wb = *(const float4*)(wcatT + (kk + dk) * 256 + c0 + 4);
      float wv0 = wa.x, wv1 = wa.y, wv2 = wa.z, wv3 = wa.w;
      float wv4 = wb.x, wv5 = wb.y, wv6 = wb.z, wv7 = wb.w;
#pragma unroll
      for (int i = 0; i < 8; ++i) {
        float xk = (dk == 0) ? xv[i].x : (dk == 1) ? xv[i].y : (dk == 2) ? xv[i].z : xv[i].w;
        acc[i][0] = fmaf(xk, wv0, acc[i][0]);
        acc[i][1] = fmaf(xk, wv1, acc[i][1]);
        acc[i][2] = fmaf(xk, wv2, acc[i][2]);
        acc[i][3] = fmaf(xk, wv3, acc[i][3]);
        acc[i][4] = fmaf(xk, wv4, acc[i][4]);
        acc[i][5] = fmaf(xk, wv5, acc[i][5]);
        acc[i][6] = fmaf(xk, wv6, acc[i][6]);
        acc[i][7] = fmaf(xk, wv7, acc[i][7]);
      }
    }
  }
  float bias[8];
#pragma unroll
  for (int j = 0; j < 8; ++j) bias[j] = (c0 < D) ? bl[c0 + j] : br[c0 - D + j];
#pragma unroll
  for (int i = 0; i < 8; ++i) {
    int gr = row0 + r0 + i;
    if (gr >= nrows) continue;
    float* base = (c0 < D) ? (hl + (size_t)gr * D + c0) : (hr + (size_t)gr * D + (c0 - D));
    float4 o0 = make_float4(acc[i][0] + bias[0], acc[i][1] + bias[1],
                            acc[i][2] + bias[2], acc[i][3] + bias[3]);
    float4 o1 = make_float4(acc[i][4] + bias[4], acc[i][5] + bias[5],
                            acc[i][6] + bias[6], acc[i][7] + bias[7]);
    *(float4*)(base) = o0;
    *(float4*)(base + 4) = o1;
  }
}

// ---------- per-node fused softmax + aggregation (1 wave per node, 4 edges in flight) ----------

__device__ __forceinline__ float2 ld2(const float* p) { return *(const float2*)p; }
__device__ __forceinline__ float2 ld2nt(const float* p) {
  float2 r;
  r.x = __builtin_nontemporal_load(p);
  r.y = __builtin_nontemporal_load(p + 1);
  return r;
}

__global__ __launch_bounds__(256) void node_attn(const float* __restrict__ x,
    const float* __restrict__ alpha, const float* __restrict__ hl,
    const float* __restrict__ hr, const int* __restrict__ perm,
    const int* __restrict__ sperm, const int* __restrict__ offsets,
    float* __restrict__ out, int n) {
  int wid = threadIdx.x >> 6, lane = threadIdx.x & 63;
  int v = (blockIdx.x << 2) + wid;
  if (v >= n) return;
  int b = offsets[v], e = offsets[v + 1];
  int ch = lane << 1;
  float2 hrv = ld2(hr + (size_t)v * D + ch);
  float dx = 0.f, dy = 0.f, ox = 0.f, oy = 0.f;

  int i = b;
  for (; i + 4 <= e; i += 4) {
    // wave-uniform index loads (scalar cache)
    int ed0 = perm[i], ed1 = perm[i + 1], ed2 = perm[i + 2], ed3 = perm[i + 3];
    int s0 = sperm[i], s1 = sperm[i + 1], s2 = sperm[i + 2], s3 = sperm[i + 3];
    // issue all 12 row-gathers before consuming
    float2 a0 = ld2nt(alpha + (size_t)ed0 * D + ch);
    float2 a1 = ld2nt(alpha + (size_t)ed1 * D + ch);
    float2 a2 = ld2nt(alpha + (size_t)ed2 * D + ch);
    float2 a3 = ld2nt(alpha + (size_t)ed3 * D + ch);
    float2 h0 = ld2(hl + (size_t)s0 * D + ch);
    float2 h1 = ld2(hl + (size_t)s1 * D + ch);
    float2 h2 = ld2(hl + (size_t)s2 * D + ch);
    float2 h3 = ld2(hl + (size_t)s3 * D + ch);
    float2 x0 = ld2(x + (size_t)s0 * D + ch);
    float2 x1 = ld2(x + (size_t)s1 * D + ch);
    float2 x2 = ld2(x + (size_t)s2 * D + ch);
    float2 x3 = ld2(x + (size_t)s3 * D + ch);

    float t0, t1;
#define STEP(hk, ak, xk)                                    \
    t0 = (hk.x + hrv.x) * ak.x;                             \
    t1 = (hk.y + hrv.y) * ak.y;                             \
    t0 = (t0 >= 0.f) ? t0 : SLOPE * t0;                     \
    t1 = (t1 >= 0.f) ? t1 : SLOPE * t1;                     \
    t0 = __expf(t0);                                        \
    t1 = __expf(t1);                                        \
    dx += t0;  dy += t1;                                    \
    ox = fmaf(xk.x, t0, ox);  oy = fmaf(xk.y, t1, oy);
    STEP(h0, a0, x0)
    STEP(h1, a1, x1)
    STEP(h2, a2, x2)
    STEP(h3, a3, x3)
#undef STEP
  }
  for (; i < e; ++i) {
    int ed = perm[i];
    int s = sperm[i];
    float2 a = ld2nt(alpha + (size_t)ed * D + ch);
    float2 h = ld2(hl + (size_t)s * D + ch);
    float2 xv = ld2(x + (size_t)s * D + ch);
    float t0 = (h.x + hrv.x) * a.x;
    float t1 = (h.y + hrv.y) * a.y;
    t0 = (t0 >= 0.f) ? t0 : SLOPE * t0;
    t1 = (t1 >= 0.f) ? t1 : SLOPE * t1;
    float e0 = __expf(t0);
    float e1 = __expf(t1);
    dx += e0;
    dy += e1;
    ox = fmaf(xv.x, e0, ox);
    oy = fmaf(xv.y, e1, oy);
  }
  float2 r;
  r.x = (e > b) ? ox / dx : 0.f;
  r.y = (e > b) ? oy / dy : 0.f;
  *(float2*)(out + (size_t)v * D + ch) = r;
}

extern "C" void kernel_launch(void* const* d_in, const int* in_sizes, int n_in,
                              void* d_out, int out_size, void* d_ws, size_t ws_size,
                              hipStream_t stream) {
  const float* x = (const float*)d_in[0];
  const float* alpha = (const float*)d_in[1];
  const float* Wl = (const float*)d_in[2];
  const float* bl = (const float*)d_in[3];
  const float* Wr = (const float*)d_in[4];
  const float* br = (const float*)d_in[5];
  const int* src = (const int*)d_in[6];
  const int* dst = (const int*)d_in[7];
  int N = in_sizes[0] / D;
  int E = in_sizes[6];
  float* out = (float*)d_out;

  char* ws = (char*)d_ws;
  auto al = [](size_t v) { return (v + 255) & ~(size_t)255; };
  size_t off = 0;
  float* hl = (float*)(ws + off); off += al((size_t)N * D * 4);
  float* hr = (float*)(ws + off); off += al((size_t)N * D * 4);
  float* wcatT = (float*)(ws + off); off += al(128 * 256 * 4);
  int* counts = (int*)(ws + off); off += al((size_t)N * 4);
  int* offsets = (int*)(ws + off); off += al((size_t)(N + 1) * 4);
  int* cursor = (int*)(ws + off); off += al((size_t)N * 4);
  int* perm = (int*)(ws + off); off += al((size_t)E * 4);
  int* sperm = (int*)(ws + off); off += al((size_t)E * 4);
  (void)off; (void)ws_size; (void)n_in; (void)out_size;

  const int tb = 256;
  hipMemsetAsync(counts, 0, (size_t)N * 4, stream);
  hist_kernel<<<(E + tb - 1) / tb, tb, 0, stream>>>(dst, counts, E);
  scan_kernel<<<1, 1024, 0, stream>>>(counts, offsets, cursor, N);
  scatter_kernel<<<(E + tb - 1) / tb, tb, 0, stream>>>(dst, src, cursor, perm, sperm, E);
  transpose_w<<<(128 * 256) / tb, tb, 0, stream>>>(Wl, Wr, wcatT);
  gemm_hlr<<<(N + 63) / 64, 256, 0, stream>>>(x, wcatT, bl, br, hl, hr, N);
  node_attn<<<(N + 3) / 4, 256, 0, stream>>>(x, alpha, hl, hr, perm, sperm, offsets, out, N);
}